// Round 6
// baseline (6195.873 us; speedup 1.0000x reference)
//
#include <hip/hip_runtime.h>

// LSTM_87771951661891: persistent kernel, tagged self-validating exchange.
// Grid 256 = 16 row-groups x 16 j-blocks; block = rows [mg*16,+16), cols
// [jb*32,+32); wave owns 8 cols. Swapped-operand MFMA -> pointwise lane-local:
// lane (l15,kg) of wave w owns (row row0+l15, cols {j0+8w+kg, j0+8w+4+kg}).
// Exchange: hbuf dwords = (bf16<<16)|step_tag via relaxed agent atomics.
// Consumer: poll optimistic per-wave flags, then load granules and validate
// embedded tags (retry if stale). No vmcnt ack, no LDS hop, no fences.

#define TN 512
#define BM 256
#define HD 512
#define ID 256

typedef __attribute__((ext_vector_type(8))) __bf16 bf16x8;
typedef __attribute__((ext_vector_type(4))) unsigned int u32x4;
typedef __attribute__((ext_vector_type(4))) float f32x4;

union ABits { u32x4 u; bf16x8 b; };
union BF16U { __bf16 b; unsigned short u; };

__device__ __forceinline__ float sigm(float x) { return 1.f / (1.f + __expf(-x)); }
__device__ __forceinline__ float tanh_fast(float x) { return 1.f - 2.f / (__expf(2.f * x) + 1.f); }

__device__ __forceinline__ unsigned long long aload64(const unsigned int* p) {
    return __hip_atomic_load((const unsigned long long*)p,
                             __ATOMIC_RELAXED, __HIP_MEMORY_SCOPE_AGENT);
}
__device__ __forceinline__ void astore32(unsigned int* p, unsigned int v) {
    __hip_atomic_store(p, v, __ATOMIC_RELAXED, __HIP_MEMORY_SCOPE_AGENT);
}

__global__ void __launch_bounds__(256, 1)
lstm_persist(const float* __restrict__ x_in, const int* __restrict__ bs_in,
             const float* __restrict__ h0, const float* __restrict__ c0_in,
             const float* __restrict__ tau_p, const float* __restrict__ Ww,
             const float* __restrict__ Wb, const float* __restrict__ Uw,
             float* __restrict__ out, unsigned int* __restrict__ hbuf,
             int* __restrict__ flags)
{
    __shared__ int   bs_lds[TN];
    __shared__ float x0_lds[16][ID + 1];

    const int tid  = threadIdx.x;
    const int lane = tid & 63;
    const int w    = tid >> 6;
    const int bid  = blockIdx.x;
    const int mg   = bid >> 4;
    const int jb   = bid & 15;
    const int row0 = mg * 16;
    const int j0   = jb * 32;
    const int l15  = lane & 15;          // row index m - row0
    const int kg   = lane >> 4;          // k-chunk id / hidden-subcol
    const int gq   = lane & 3;           // ub build
    const int jjq  = l15 >> 2;           // ub build
    const float tau = tau_p[0];

    // ---------------- prologue ----------------
    for (int i = tid; i < TN; i += 256) bs_lds[i] = bs_in[i];
    for (int s = tid; s < 16 * (ID / 4); s += 256) {
        int r = s >> 6, cs = s & 63;
        *reinterpret_cast<float4*>(&x0_lds[r][cs * 4]) =
            reinterpret_cast<const float4*>(x_in + (size_t)(row0 + r) * ID)[cs];
    }
    __syncthreads();

    // Gx = x0 @ Ww + Wb for this lane's 8 gates: (m=l15, col=g*512+j0+8w+4f+kg)
    float gxv[2][4];
    {
        float a[2][4] = {};
        const int cbase = j0 + 8 * w + kg;
        for (int k = 0; k < ID; ++k) {
            float xv = x0_lds[l15][k];
            const float* wr = Ww + (size_t)k * 2048;
            #pragma unroll
            for (int g = 0; g < 4; ++g) {
                a[0][g] += xv * wr[g * HD + cbase];
                a[1][g] += xv * wr[g * HD + cbase + 4];
            }
        }
        #pragma unroll
        for (int g = 0; g < 4; ++g) {
            gxv[0][g] = a[0][g] + Wb[g * HD + cbase];
            gxv[1][g] = a[1][g] + Wb[g * HD + cbase + 4];
        }
    }

    // U slice -> registers (A-operand = U^T). col(l15) = gq*512 + j0+8w+4f+jjq
    bf16x8 ub[2][16];
    #pragma unroll
    for (int f = 0; f < 2; ++f) {
        const int ucol = gq * HD + j0 + 8 * w + 4 * f + jjq;
        #pragma unroll
        for (int ki = 0; ki < 16; ++ki) {
            const int kb = ki * 32 + kg * 8;
            bf16x8 v;
            #pragma unroll
            for (int e = 0; e < 8; ++e) v[e] = (__bf16)Uw[(size_t)(kb + e) * 2048 + ucol];
            ub[f][ki] = v;
        }
    }

    // lane-local state: row m, cols {c0, c0+4}
    const int m  = row0 + l15;
    const int c0 = j0 + 8 * w + kg;
    const bool owner = (jb == 0) && (w == 0) && (kg < 2);   // exact col 0/1 channel (f=0)
    float creg[2], hprev2[2], hxy = 0.f;
    creg[0] = c0_in[(size_t)m * HD + c0];
    creg[1] = c0_in[(size_t)m * HD + c0 + 4];

    {
        float v0 = h0[(size_t)m * HD + c0];
        float v1 = h0[(size_t)m * HD + c0 + 4];
        hprev2[0] = v0; hprev2[1] = v1;
        if (owner) hxy = v0;
        BF16U b0, b1; b0.b = (__bf16)v0; b1.b = (__bf16)v1;
        astore32(hbuf + (size_t)m * HD + c0,     ((unsigned int)b0.u << 16) | 1u);
        astore32(hbuf + (size_t)m * HD + c0 + 4, ((unsigned int)b1.u << 16) | 1u);
        __builtin_amdgcn_sched_barrier(0);
        if (lane == 0)
            __hip_atomic_store(&flags[mg * 64 + jb * 4 + w], 1,
                               __ATOMIC_RELAXED, __HIP_MEMORY_SCOPE_AGENT);
    }

    // ---------------- main sequential loop ----------------
    for (int t = 0; t < TN; ++t) {
        const int bs_t = bs_lds[t];
        const bool act = m < bs_t;

        // advance exact xcorr channel (owner lanes; junk elsewhere is unused)
        if (t != 0) {
            float other = __shfl_xor(hxy, 16);
            hxy = hxy + tau * (((kg & 1) == 0) ? (1.5f * hxy + 0.66666667f * other)
                                               : (-1.5f * other));
        }

        // optimistic flag gate
        for (;;) {
            int v = __hip_atomic_load(&flags[mg * 64 + lane],
                                      __ATOMIC_RELAXED, __HIP_MEMORY_SCOPE_AGENT);
            if (__all(v >= t + 1)) break;
            __builtin_amdgcn_s_sleep(1);
        }

        // tagged loads + validation (retry until all 128 tags match)
        const unsigned int* arow =
            hbuf + (size_t)(t & 1) * (BM * HD) + (size_t)m * HD + kg * 8;
        const unsigned long long want  = (unsigned long long)((t + 1) & 0xFFFF);
        const unsigned long long wantp = want | (want << 32);
        bf16x8 ah[16];
        for (;;) {
            unsigned long long diff = 0ull;
            #pragma unroll
            for (int ki = 0; ki < 16; ++ki) {
                unsigned long long g0 = aload64(arow + ki * 32 + 0);
                unsigned long long g1 = aload64(arow + ki * 32 + 2);
                unsigned long long g2 = aload64(arow + ki * 32 + 4);
                unsigned long long g3 = aload64(arow + ki * 32 + 6);
                diff |= (g0 ^ wantp) & 0x0000FFFF0000FFFFull;
                diff |= (g1 ^ wantp) & 0x0000FFFF0000FFFFull;
                diff |= (g2 ^ wantp) & 0x0000FFFF0000FFFFull;
                diff |= (g3 ^ wantp) & 0x0000FFFF0000FFFFull;
                ABits a;
                a.u[0] = (unsigned int)((g0 >> 16) & 0xFFFFu) | (unsigned int)((g0 >> 32) & 0xFFFF0000u);
                a.u[1] = (unsigned int)((g1 >> 16) & 0xFFFFu) | (unsigned int)((g1 >> 32) & 0xFFFF0000u);
                a.u[2] = (unsigned int)((g2 >> 16) & 0xFFFFu) | (unsigned int)((g2 >> 32) & 0xFFFF0000u);
                a.u[3] = (unsigned int)((g3 >> 16) & 0xFFFFu) | (unsigned int)((g3 >> 32) & 0xFFFF0000u);
                ah[ki] = a.b;
            }
            if (__all(diff == 0ull)) break;
            __builtin_amdgcn_s_sleep(1);
        }

        // read-side xcorr on k=0,1 (all rows; t!=0)
        if (t != 0 && kg == 0) {
            float xs0 = (float)ah[0][0];
            float xs1 = (float)ah[0][1];
            ah[0][0] = (__bf16)(xs0 + tau * (1.5f * xs0 + 0.66666667f * xs1));
            ah[0][1] = (__bf16)(xs1 + tau * (-1.5f * xs0));
        }

        // gates = U^T x h^T (swapped operands)
        f32x4 acc0 = {0.f, 0.f, 0.f, 0.f}, acc1 = {0.f, 0.f, 0.f, 0.f};
        #pragma unroll
        for (int ki = 0; ki < 16; ++ki) {
            acc0 = __builtin_amdgcn_mfma_f32_16x16x32_bf16(ub[0][ki], ah[ki], acc0, 0, 0, 0);
            acc1 = __builtin_amdgcn_mfma_f32_16x16x32_bf16(ub[1][ki], ah[ki], acc1, 0, 0, 0);
        }

        // pointwise + direct tagged stores (lane-local carry)
        unsigned int* nrow = hbuf + (size_t)((t + 1) & 1) * (BM * HD) + (size_t)m * HD;
        const unsigned int ntag = (unsigned int)((t + 2) & 0xFFFF);
        float outv[2];
        #pragma unroll
        for (int f = 0; f < 2; ++f) {
            const f32x4 a = f ? acc1 : acc0;
            float gi = a[0] + gxv[f][0];
            float gf = a[1] + gxv[f][1];
            float gg = a[2] + gxv[f][2];
            float go = a[3] + gxv[f][3];
            float cn = sigm(gf) * creg[f] + sigm(gi) * tanh_fast(gg);
            float hn = sigm(go) * tanh_fast(cn);
            if (act) creg[f] = cn;
            float hs;
            if (f == 0 && owner) {
                hxy = act ? hn : hxy;
                hs = hxy;
            } else {
                hs = act ? hn : hprev2[f];
            }
            hprev2[f] = hs;
            BF16U cv; cv.b = (__bf16)hs;
            astore32(nrow + c0 + 4 * f, ((unsigned int)cv.u << 16) | ntag);
            outv[f] = act ? hn : 0.f;
        }
        __builtin_amdgcn_sched_barrier(0);
        if (lane == 0)
            __hip_atomic_store(&flags[mg * 64 + jb * 4 + w], t + 2,
                               __ATOMIC_RELAXED, __HIP_MEMORY_SCOPE_AGENT);

        // outputs[t] off the critical path
        float* orow = out + (size_t)t * (BM * HD) + (size_t)m * HD;
        orow[c0]     = outv[0];
        orow[c0 + 4] = outv[1];
    }

    // ---------------- epilogue ----------------
    float* hp = out + (size_t)TN * BM * HD;
    hp[(size_t)m * HD + c0]     = hprev2[0];
    hp[(size_t)m * HD + c0 + 4] = hprev2[1];
    float* cp = out + (size_t)TN * BM * HD + (size_t)BM * HD;
    cp[(size_t)m * HD + c0]     = creg[0];
    cp[(size_t)m * HD + c0 + 4] = creg[1];
}

extern "C" void kernel_launch(void* const* d_in, const int* in_sizes, int n_in,
                              void* d_out, int out_size, void* d_ws, size_t ws_size,
                              hipStream_t stream) {
    const float* x_in = (const float*)d_in[0];
    const int*   bs   = (const int*)d_in[1];
    const float* h0   = (const float*)d_in[2];
    const float* c0   = (const float*)d_in[3];
    const float* tau  = (const float*)d_in[4];
    const float* Ww   = (const float*)d_in[5];
    const float* Wb   = (const float*)d_in[6];
    const float* Uw   = (const float*)d_in[7];
    float* out = (float*)d_out;

    int*          flags = (int*)d_ws;                          // 16 x 64 ints = 4 KB
    unsigned int* hbuf  = (unsigned int*)((char*)d_ws + 4096); // 2 x 256 x 512 u32 = 1 MB

    // zero flags AND tags every call (no cross-call state)
    (void)hipMemsetAsync(d_ws, 0, 4096 + 2 * BM * HD * sizeof(unsigned int), stream);

    hipLaunchKernelGGL(lstm_persist, dim3(256), dim3(256), 0, stream,
                       x_in, bs, h0, c0, tau, Ww, Wb, Uw, out, hbuf, flags);
}

// Round 7
// 3649.725 us; speedup vs baseline: 1.6976x; 1.6976x over previous
//
#include <hip/hip_runtime.h>

// LSTM_87771951661891: persistent kernel, wave-autonomous steps (R5 base).
// Grid 256 = 16 row-groups x 16 j-blocks; block = rows [mg*16,+16), cols
// [jb*32,+32); wave owns 8 cols. Swapped-operand MFMA -> pointwise lane-local.
// h state (bf16) double-buffered in d_ws; producer: relaxed agent atomic
// 64-bit stores + s_waitcnt vmcnt(0) + per-wave monotonic flag. Consumer:
// poll flags, then UC (sc0 sc1) dwordx4 inline-asm loads of h fragments
// (same bypass semantics as atomic loads, half the requests).

#define TN 512
#define BM 256
#define HD 512
#define ID 256

typedef __attribute__((ext_vector_type(8))) __bf16 bf16x8;
typedef __attribute__((ext_vector_type(4))) __bf16 bf16x4;
typedef __attribute__((ext_vector_type(4))) unsigned int u32x4;
typedef __attribute__((ext_vector_type(4))) float f32x4;

union ABits { u32x4 u; bf16x8 b; };
union U64x1 { bf16x4 v; unsigned long long q; };

__device__ __forceinline__ float sigm(float x) { return 1.f / (1.f + __expf(-x)); }
__device__ __forceinline__ float tanh_fast(float x) { return 1.f - 2.f / (__expf(2.f * x) + 1.f); }

__device__ __forceinline__ void astore64(__bf16* p, unsigned long long v) {
    __hip_atomic_store((unsigned long long*)p, v,
                       __ATOMIC_RELAXED, __HIP_MEMORY_SCOPE_AGENT);
}

__global__ void __launch_bounds__(256, 1)
lstm_persist(const float* __restrict__ x_in, const int* __restrict__ bs_in,
             const float* __restrict__ h0, const float* __restrict__ c0,
             const float* __restrict__ tau_p, const float* __restrict__ Ww,
             const float* __restrict__ Wb, const float* __restrict__ Uw,
             float* __restrict__ out, __bf16* __restrict__ hbuf,
             int* __restrict__ flags)
{
    __shared__ int   bs_lds[TN];
    __shared__ float x0_lds[16][ID + 1];      // padded (bank-conflict-free)
    __shared__ float hn_patch[4][16][9];      // per-wave h_new transpose patch

    const int tid  = threadIdx.x;
    const int lane = tid & 63;
    const int w    = tid >> 6;           // wave 0..3
    const int bid  = blockIdx.x;
    const int mg   = bid >> 4;           // row-group
    const int jb   = bid & 15;           // j-block
    const int row0 = mg * 16;
    const int j0   = jb * 32;
    const int l15  = lane & 15;          // MFMA row (m) for B-frag / output col
    const int kg   = lane >> 4;          // k-chunk id; also hidden-subcol in output
    const int gq   = lane & 3;           // ub build: gate index of MFMA-col l15
    const int jjq  = l15 >> 2;           // ub build: hidden-subcol of MFMA-col l15
    const float tau = tau_p[0];

    // ---------------- prologue ----------------
    for (int i = tid; i < TN; i += 256) bs_lds[i] = bs_in[i];
    for (int s = tid; s < 16 * (ID / 4); s += 256) {
        int r = s >> 6, cs = s & 63;
        *reinterpret_cast<float4*>(&x0_lds[r][cs * 4]) =
            reinterpret_cast<const float4*>(x_in + (size_t)(row0 + r) * ID)[cs];
    }
    __syncthreads();

    // Gx = x0 @ Ww + Wb for this lane's 8 output gates:
    // (row m=l15, col = g*512 + j0 + 8w + 4f + kg), f in {0,1}, g in {0..3}
    float gxv[2][4];
    {
        float a[2][4] = {};
        const int cbase = j0 + 8 * w + kg;
        for (int k = 0; k < ID; ++k) {
            float xv = x0_lds[l15][k];
            const float* wr = Ww + (size_t)k * 2048;
            #pragma unroll
            for (int g = 0; g < 4; ++g) {
                a[0][g] += xv * wr[g * HD + cbase];
                a[1][g] += xv * wr[g * HD + cbase + 4];
            }
        }
        #pragma unroll
        for (int g = 0; g < 4; ++g) {
            gxv[0][g] = a[0][g] + Wb[g * HD + cbase];
            gxv[1][g] = a[1][g] + Wb[g * HD + cbase + 4];
        }
    }

    // U slice -> registers. Fragment: lane holds k-slice kg*8+e of MFMA-col l15,
    // col(l15) = gq*512 + j0 + 8w + 4f + jjq  (used as A-operand = U^T)
    bf16x8 ub[2][16];
    #pragma unroll
    for (int f = 0; f < 2; ++f) {
        const int ucol = gq * HD + j0 + 8 * w + 4 * f + jjq;
        #pragma unroll
        for (int ki = 0; ki < 16; ++ki) {
            const int kb = ki * 32 + kg * 8;
            bf16x8 v;
            #pragma unroll
            for (int e = 0; e < 8; ++e) v[e] = (__bf16)Uw[(size_t)(kb + e) * 2048 + ucol];
            ub[f][ki] = v;
        }
    }

    // c state: lane-local, (row m=l15, col j0+8w+4f+kg)
    float creg[2];
    #pragma unroll
    for (int f = 0; f < 2; ++f)
        creg[f] = c0[(size_t)(row0 + l15) * HD + j0 + 8 * w + 4 * f + kg];

    // store-lane setup (lane<32): r=lane>>1, s=lane&1 -> 4 cols jc..jc+3
    const int sr = lane >> 1, ss = lane & 1;
    const int jc = j0 + 8 * w + 4 * ss;
    const bool is_store = (lane < 32);
    const bool owner = (jb == 0) && (w == 0) && (ss == 0) && is_store; // cols 0..3, hxy for 0,1
    float hprev[4] = {0.f, 0.f, 0.f, 0.f};
    float hxy0 = 0.f, hxy1 = 0.f;

    if (is_store) {
        float4 v = *reinterpret_cast<const float4*>(h0 + (size_t)(row0 + sr) * HD + jc);
        hprev[0] = v.x; hprev[1] = v.y; hprev[2] = v.z; hprev[3] = v.w;
        if (owner) { hxy0 = v.x; hxy1 = v.y; }
        U64x1 sv;
        #pragma unroll
        for (int c = 0; c < 4; ++c) sv.v[c] = (__bf16)hprev[c];
        astore64(hbuf + (size_t)(row0 + sr) * HD + jc, sv.q);
    }
    asm volatile("s_waitcnt vmcnt(0)" ::: "memory");
    __builtin_amdgcn_sched_barrier(0);
    if (lane == 0)
        __hip_atomic_store(&flags[mg * 64 + jb * 4 + w], 1,
                           __ATOMIC_RELAXED, __HIP_MEMORY_SCOPE_AGENT);

    // ---------------- main sequential loop ----------------
    for (int t = 0; t < TN; ++t) {
        const __bf16* base_p = hbuf + (size_t)(t & 1) * (BM * HD);
        __bf16*       base_n = hbuf + (size_t)((t + 1) & 1) * (BM * HD);
        const int bs_t = bs_lds[t];

        // fp32 xcorr side-channel advance (owner lanes; harmless elsewhere)
        if (t != 0) {
            float xs0 = hxy0, xs1 = hxy1;
            hxy0 = xs0 + tau * (1.5f * xs0 + 0.66666667f * xs1);
            hxy1 = xs1 + tau * (-1.5f * xs0);
        }

        // spin: all 64 producer-wave flags of this row-group >= t+1
        for (;;) {
            int v = __hip_atomic_load(&flags[mg * 64 + lane],
                                      __ATOMIC_RELAXED, __HIP_MEMORY_SCOPE_AGENT);
            if (__all(v >= t + 1)) break;
            __builtin_amdgcn_s_sleep(1);
        }

        // h fragments: 16 x UC dwordx4 loads (bypass L1+L2, read coherence point)
        const __bf16* arow = base_p + (size_t)(row0 + l15) * HD + kg * 8;
        u32x4 r0,r1,r2,r3,r4,r5,r6,r7,r8,r9,r10,r11,r12,r13,r14,r15;
        asm volatile(
            "global_load_dwordx4 %0, %[p], off sc0 sc1\n\t"
            "global_load_dwordx4 %1, %[p], off offset:64 sc0 sc1\n\t"
            "global_load_dwordx4 %2, %[p], off offset:128 sc0 sc1\n\t"
            "global_load_dwordx4 %3, %[p], off offset:192 sc0 sc1\n\t"
            "global_load_dwordx4 %4, %[p], off offset:256 sc0 sc1\n\t"
            "global_load_dwordx4 %5, %[p], off offset:320 sc0 sc1\n\t"
            "global_load_dwordx4 %6, %[p], off offset:384 sc0 sc1\n\t"
            "global_load_dwordx4 %7, %[p], off offset:448 sc0 sc1\n\t"
            "global_load_dwordx4 %8, %[p], off offset:512 sc0 sc1\n\t"
            "global_load_dwordx4 %9, %[p], off offset:576 sc0 sc1\n\t"
            "global_load_dwordx4 %10, %[p], off offset:640 sc0 sc1\n\t"
            "global_load_dwordx4 %11, %[p], off offset:704 sc0 sc1\n\t"
            "global_load_dwordx4 %12, %[p], off offset:768 sc0 sc1\n\t"
            "global_load_dwordx4 %13, %[p], off offset:832 sc0 sc1\n\t"
            "global_load_dwordx4 %14, %[p], off offset:896 sc0 sc1\n\t"
            "global_load_dwordx4 %15, %[p], off offset:960 sc0 sc1\n\t"
            "s_waitcnt vmcnt(0)"
            : "=&v"(r0), "=&v"(r1), "=&v"(r2), "=&v"(r3),
              "=&v"(r4), "=&v"(r5), "=&v"(r6), "=&v"(r7),
              "=&v"(r8), "=&v"(r9), "=&v"(r10), "=&v"(r11),
              "=&v"(r12), "=&v"(r13), "=&v"(r14), "=&v"(r15)
            : [p] "v"(arow)
            : "memory");
        __builtin_amdgcn_sched_barrier(0);

        bf16x8 ah[16];
        {
            ABits tb;
            tb.u = r0;  ah[0]  = tb.b;  tb.u = r1;  ah[1]  = tb.b;
            tb.u = r2;  ah[2]  = tb.b;  tb.u = r3;  ah[3]  = tb.b;
            tb.u = r4;  ah[4]  = tb.b;  tb.u = r5;  ah[5]  = tb.b;
            tb.u = r6;  ah[6]  = tb.b;  tb.u = r7;  ah[7]  = tb.b;
            tb.u = r8;  ah[8]  = tb.b;  tb.u = r9;  ah[9]  = tb.b;
            tb.u = r10; ah[10] = tb.b;  tb.u = r11; ah[11] = tb.b;
            tb.u = r12; ah[12] = tb.b;  tb.u = r13; ah[13] = tb.b;
            tb.u = r14; ah[14] = tb.b;  tb.u = r15; ah[15] = tb.b;
        }

        // read-side xcorr on k=0,1 (all rows; t!=0), fp32
        if (t != 0 && kg == 0) {
            float xs0 = (float)ah[0][0];
            float xs1 = (float)ah[0][1];
            ah[0][0] = (__bf16)(xs0 + tau * (1.5f * xs0 + 0.66666667f * xs1));
            ah[0][1] = (__bf16)(xs1 + tau * (-1.5f * xs0));
        }

        // gates = U^T x h^T  (swapped operands): acc[f][g] for (m=l15, col 8w+4f+kg)
        f32x4 acc0 = {0.f, 0.f, 0.f, 0.f}, acc1 = {0.f, 0.f, 0.f, 0.f};
        #pragma unroll
        for (int ki = 0; ki < 16; ++ki) {
            acc0 = __builtin_amdgcn_mfma_f32_16x16x32_bf16(ub[0][ki], ah[ki], acc0, 0, 0, 0);
            acc1 = __builtin_amdgcn_mfma_f32_16x16x32_bf16(ub[1][ki], ah[ki], acc1, 0, 0, 0);
        }

        // pointwise: fully lane-local (4 gates per hidden unit in-register)
        const bool act_m = (row0 + l15) < bs_t;
        #pragma unroll
        for (int f = 0; f < 2; ++f) {
            const f32x4 a = f ? acc1 : acc0;
            float gi = a[0] + gxv[f][0];
            float gf = a[1] + gxv[f][1];
            float gg = a[2] + gxv[f][2];
            float go = a[3] + gxv[f][3];
            float cn = sigm(gf) * creg[f] + sigm(gi) * tanh_fast(gg);
            float hn = sigm(go) * tanh_fast(cn);
            if (act_m) creg[f] = cn;
            hn_patch[w][l15][4 * f + kg] = hn;
        }

        // wave-local transpose barrier (same-wave LDS ordering only)
        asm volatile("s_waitcnt lgkmcnt(0)" ::: "memory");
        __builtin_amdgcn_sched_barrier(0);

        // store phase: lanes 0..31, row sr, cols jc..jc+3
        if (is_store) {
            const bool act_r = (row0 + sr) < bs_t;
            float hn0 = hn_patch[w][sr][4 * ss + 0];
            float hn1 = hn_patch[w][sr][4 * ss + 1];
            float hn2 = hn_patch[w][sr][4 * ss + 2];
            float hn3 = hn_patch[w][sr][4 * ss + 3];
            float hv[4];
            hv[0] = act_r ? hn0 : hprev[0];
            hv[1] = act_r ? hn1 : hprev[1];
            hv[2] = act_r ? hn2 : hprev[2];
            hv[3] = act_r ? hn3 : hprev[3];
            if (owner) {
                if (act_r) { hxy0 = hn0; hxy1 = hn1; }
                else       { hv[0] = hxy0; hv[1] = hxy1; }
            }
            #pragma unroll
            for (int c = 0; c < 4; ++c) hprev[c] = hv[c];
            U64x1 sv;
            #pragma unroll
            for (int c = 0; c < 4; ++c) sv.v[c] = (__bf16)hv[c];
            astore64(base_n + (size_t)(row0 + sr) * HD + jc, sv.q);
            asm volatile("s_waitcnt vmcnt(0)" ::: "memory");
            __builtin_amdgcn_sched_barrier(0);
            if (lane == 0)
                __hip_atomic_store(&flags[mg * 64 + jb * 4 + w], t + 2,
                                   __ATOMIC_RELAXED, __HIP_MEMORY_SCOPE_AGENT);
            // outputs[t] (off the inter-block critical path)
            float4 q;
            q.x = act_r ? hn0 : 0.f; q.y = act_r ? hn1 : 0.f;
            q.z = act_r ? hn2 : 0.f; q.w = act_r ? hn3 : 0.f;
            *reinterpret_cast<float4*>(out + (size_t)t * (BM * HD)
                                       + (size_t)(row0 + sr) * HD + jc) = q;
        }
    }

    // ---------------- epilogue ----------------
    // final h from fp32 hprev (store-lanes)
    if (is_store) {
        float4 p;
        p.x = hprev[0]; p.y = hprev[1]; p.z = hprev[2]; p.w = hprev[3];
        *reinterpret_cast<float4*>(out + (size_t)TN * BM * HD
                                   + (size_t)(row0 + sr) * HD + jc) = p;
    }
    // final c from lane-local creg
    {
        float* cp = out + (size_t)TN * BM * HD + (size_t)BM * HD;
        #pragma unroll
        for (int f = 0; f < 2; ++f)
            cp[(size_t)(row0 + l15) * HD + j0 + 8 * w + 4 * f + kg] = creg[f];
    }
}

extern "C" void kernel_launch(void* const* d_in, const int* in_sizes, int n_in,
                              void* d_out, int out_size, void* d_ws, size_t ws_size,
                              hipStream_t stream) {
    const float* x_in = (const float*)d_in[0];
    const int*   bs   = (const int*)d_in[1];
    const float* h0   = (const float*)d_in[2];
    const float* c0   = (const float*)d_in[3];
    const float* tau  = (const float*)d_in[4];
    const float* Ww   = (const float*)d_in[5];
    const float* Wb   = (const float*)d_in[6];
    const float* Uw   = (const float*)d_in[7];
    float* out = (float*)d_out;

    int*    flags = (int*)d_ws;                      // 16 groups x 64 flags = 4 KB
    __bf16* hbuf  = (__bf16*)((char*)d_ws + 4096);   // 2 bufs x 256 x 512 bf16 = 512 KB

    (void)hipMemsetAsync(d_ws, 0, 4096, stream);

    hipLaunchKernelGGL(lstm_persist, dim3(256), dim3(256), 0, stream,
                       x_in, bs, h0, c0, tau, Ww, Wb, Uw, out, hbuf, flags);
}

// Round 8
// 2161.198 us; speedup vs baseline: 2.8669x; 1.6888x over previous
//
#include <hip/hip_runtime.h>

// LSTM_87771951661891: persistent kernel, wave-autonomous + LDS-staged h tile.
// Grid 256 = 16 row-groups x 16 j-blocks; block = rows [mg*16,+16), cols
// [jb*32,+32); wave owns 8 cols. Swapped-operand MFMA -> pointwise lane-local.
// h state (bf16) double-buffered in d_ws. Producer: relaxed agent atomic 64-bit
// stores + s_waitcnt vmcnt(0) + per-wave monotonic flag. Consumer: poll the 64
// group flags, then the 4 waves cooperatively UC-load (sc0 sc1) the 16x512
// tile into LDS (4 rows/wave, 4x dwordx4/lane), one __syncthreads, MFMA
// fragments from LDS. Cuts agent-scope read traffic 4x vs per-wave loads.

#define TN 512
#define BM 256
#define HD 512
#define ID 256

typedef __attribute__((ext_vector_type(8))) __bf16 bf16x8;
typedef __attribute__((ext_vector_type(4))) __bf16 bf16x4;
typedef __attribute__((ext_vector_type(4))) unsigned int u32x4;
typedef __attribute__((ext_vector_type(4))) float f32x4;

union ABits { u32x4 u; bf16x8 b; };
union U64x1 { bf16x4 v; unsigned long long q; };

__device__ __forceinline__ float sigm(float x) { return 1.f / (1.f + __expf(-x)); }
__device__ __forceinline__ float tanh_fast(float x) { return 1.f - 2.f / (__expf(2.f * x) + 1.f); }

__device__ __forceinline__ void astore64(__bf16* p, unsigned long long v) {
    __hip_atomic_store((unsigned long long*)p, v,
                       __ATOMIC_RELAXED, __HIP_MEMORY_SCOPE_AGENT);
}

__global__ void __launch_bounds__(256, 1)
lstm_persist(const float* __restrict__ x_in, const int* __restrict__ bs_in,
             const float* __restrict__ h0, const float* __restrict__ c0,
             const float* __restrict__ tau_p, const float* __restrict__ Ww,
             const float* __restrict__ Wb, const float* __restrict__ Uw,
             float* __restrict__ out, __bf16* __restrict__ hbuf,
             int* __restrict__ flags)
{
    __shared__ int   bs_lds[TN];
    __shared__ float x0_lds[16][ID + 1];            // prologue only
    __shared__ float hn_patch[4][16][9];            // per-wave h_new transpose patch
    __shared__ __align__(16) __bf16 htile[16][520]; // staged h tile (+16B row pad)

    const int tid  = threadIdx.x;
    const int lane = tid & 63;
    const int w    = tid >> 6;           // wave 0..3
    const int bid  = blockIdx.x;
    const int mg   = bid >> 4;           // row-group
    const int jb   = bid & 15;           // j-block
    const int row0 = mg * 16;
    const int j0   = jb * 32;
    const int l15  = lane & 15;          // MFMA row (m) / B-frag col
    const int kg   = lane >> 4;          // k-chunk id; hidden-subcol in output
    const int gq   = lane & 3;           // ub build: gate index of MFMA-col l15
    const int jjq  = l15 >> 2;           // ub build: hidden-subcol of MFMA-col l15
    const float tau = tau_p[0];

    // staging assignment: wave w stages rows 4w..4w+3; lane -> (row, 16B slot)
    const int srow = 4 * w + (lane >> 4);           // local row 0..15
    const int scol = (lane & 15) * 8;               // element offset in row (16B slot)

    // ---------------- prologue ----------------
    for (int i = tid; i < TN; i += 256) bs_lds[i] = bs_in[i];
    for (int s = tid; s < 16 * (ID / 4); s += 256) {
        int r = s >> 6, cs = s & 63;
        *reinterpret_cast<float4*>(&x0_lds[r][cs * 4]) =
            reinterpret_cast<const float4*>(x_in + (size_t)(row0 + r) * ID)[cs];
    }
    __syncthreads();

    // Gx = x0 @ Ww + Wb for this lane's 8 output gates:
    // (row m=l15, col = g*512 + j0 + 8w + 4f + kg), f in {0,1}, g in {0..3}
    float gxv[2][4];
    {
        float a[2][4] = {};
        const int cbase = j0 + 8 * w + kg;
        for (int k = 0; k < ID; ++k) {
            float xv = x0_lds[l15][k];
            const float* wr = Ww + (size_t)k * 2048;
            #pragma unroll
            for (int g = 0; g < 4; ++g) {
                a[0][g] += xv * wr[g * HD + cbase];
                a[1][g] += xv * wr[g * HD + cbase + 4];
            }
        }
        #pragma unroll
        for (int g = 0; g < 4; ++g) {
            gxv[0][g] = a[0][g] + Wb[g * HD + cbase];
            gxv[1][g] = a[1][g] + Wb[g * HD + cbase + 4];
        }
    }

    // U slice -> registers. lane holds k-slice kg*8+e of MFMA-col l15,
    // col(l15) = gq*512 + j0 + 8w + 4f + jjq  (A-operand = U^T)
    bf16x8 ub[2][16];
    #pragma unroll
    for (int f = 0; f < 2; ++f) {
        const int ucol = gq * HD + j0 + 8 * w + 4 * f + jjq;
        #pragma unroll
        for (int ki = 0; ki < 16; ++ki) {
            const int kb = ki * 32 + kg * 8;
            bf16x8 v;
            #pragma unroll
            for (int e = 0; e < 8; ++e) v[e] = (__bf16)Uw[(size_t)(kb + e) * 2048 + ucol];
            ub[f][ki] = v;
        }
    }

    // c state: lane-local, (row m=l15, col j0+8w+4f+kg)
    float creg[2];
    #pragma unroll
    for (int f = 0; f < 2; ++f)
        creg[f] = c0[(size_t)(row0 + l15) * HD + j0 + 8 * w + 4 * f + kg];

    // store-lane setup (lane<32): r=lane>>1, s=lane&1 -> 4 cols jc..jc+3
    const int sr = lane >> 1, ss = lane & 1;
    const int jc = j0 + 8 * w + 4 * ss;
    const bool is_store = (lane < 32);
    const bool owner = (jb == 0) && (w == 0) && (ss == 0) && is_store;
    float hprev[4] = {0.f, 0.f, 0.f, 0.f};
    float hxy0 = 0.f, hxy1 = 0.f;

    if (is_store) {
        float4 v = *reinterpret_cast<const float4*>(h0 + (size_t)(row0 + sr) * HD + jc);
        hprev[0] = v.x; hprev[1] = v.y; hprev[2] = v.z; hprev[3] = v.w;
        if (owner) { hxy0 = v.x; hxy1 = v.y; }
        U64x1 sv;
        #pragma unroll
        for (int c = 0; c < 4; ++c) sv.v[c] = (__bf16)hprev[c];
        astore64(hbuf + (size_t)(row0 + sr) * HD + jc, sv.q);
    }
    asm volatile("s_waitcnt vmcnt(0)" ::: "memory");
    __builtin_amdgcn_sched_barrier(0);
    if (lane == 0)
        __hip_atomic_store(&flags[mg * 64 + jb * 4 + w], 1,
                           __ATOMIC_RELAXED, __HIP_MEMORY_SCOPE_AGENT);

    // ---------------- main sequential loop ----------------
    for (int t = 0; t < TN; ++t) {
        const __bf16* base_p = hbuf + (size_t)(t & 1) * (BM * HD);
        __bf16*       base_n = hbuf + (size_t)((t + 1) & 1) * (BM * HD);
        const int bs_t = bs_lds[t];

        // fp32 xcorr side-channel advance (owner lanes; harmless elsewhere)
        if (t != 0) {
            float xs0 = hxy0, xs1 = hxy1;
            hxy0 = xs0 + tau * (1.5f * xs0 + 0.66666667f * xs1);
            hxy1 = xs1 + tau * (-1.5f * xs0);
        }

        // spin: all 64 producer-wave flags of this row-group >= t+1.
        // A wave posts t+1 only after it consumed htile for step t, so the
        // staging writes below cannot race any reader (no extra barrier).
        for (;;) {
            int v = __hip_atomic_load(&flags[mg * 64 + lane],
                                      __ATOMIC_RELAXED, __HIP_MEMORY_SCOPE_AGENT);
            if (__all(v >= t + 1)) break;
            __builtin_amdgcn_s_sleep(1);
        }

        // cooperative UC stage: wave w loads rows 4w..4w+3 (4x dwordx4/lane,
        // 256B stride) and writes them into LDS (conflict-free 16B slots).
        {
            const __bf16* srcp = base_p + (size_t)(row0 + srow) * HD + scol;
            u32x4 s0, s1, s2, s3;
            asm volatile(
                "global_load_dwordx4 %0, %[p], off sc0 sc1\n\t"
                "global_load_dwordx4 %1, %[p], off offset:256 sc0 sc1\n\t"
                "global_load_dwordx4 %2, %[p], off offset:512 sc0 sc1\n\t"
                "global_load_dwordx4 %3, %[p], off offset:768 sc0 sc1\n\t"
                "s_waitcnt vmcnt(0)"
                : "=&v"(s0), "=&v"(s1), "=&v"(s2), "=&v"(s3)
                : [p] "v"(srcp)
                : "memory");
            __builtin_amdgcn_sched_barrier(0);
            ABits tb;
            tb.u = s0; *reinterpret_cast<bf16x8*>(&htile[srow][scol])       = tb.b;
            tb.u = s1; *reinterpret_cast<bf16x8*>(&htile[srow][scol + 128]) = tb.b;
            tb.u = s2; *reinterpret_cast<bf16x8*>(&htile[srow][scol + 256]) = tb.b;
            tb.u = s3; *reinterpret_cast<bf16x8*>(&htile[srow][scol + 384]) = tb.b;
        }
        __syncthreads();

        // h fragments from LDS: ah[ki][e] = h[row l15][ki*32 + kg*8 + e]
        bf16x8 ah[16];
        #pragma unroll
        for (int ki = 0; ki < 16; ++ki)
            ah[ki] = *reinterpret_cast<const bf16x8*>(&htile[l15][ki * 32 + kg * 8]);

        // read-side xcorr on k=0,1 (all rows; t!=0), fp32
        if (t != 0 && kg == 0) {
            float xs0 = (float)ah[0][0];
            float xs1 = (float)ah[0][1];
            ah[0][0] = (__bf16)(xs0 + tau * (1.5f * xs0 + 0.66666667f * xs1));
            ah[0][1] = (__bf16)(xs1 + tau * (-1.5f * xs0));
        }

        // gates = U^T x h^T (swapped operands): acc[f][g] for (m=l15, col 8w+4f+kg)
        f32x4 acc0 = {0.f, 0.f, 0.f, 0.f}, acc1 = {0.f, 0.f, 0.f, 0.f};
        #pragma unroll
        for (int ki = 0; ki < 16; ++ki) {
            acc0 = __builtin_amdgcn_mfma_f32_16x16x32_bf16(ub[0][ki], ah[ki], acc0, 0, 0, 0);
            acc1 = __builtin_amdgcn_mfma_f32_16x16x32_bf16(ub[1][ki], ah[ki], acc1, 0, 0, 0);
        }

        // pointwise: fully lane-local (4 gates per hidden unit in-register)
        const bool act_m = (row0 + l15) < bs_t;
        #pragma unroll
        for (int f = 0; f < 2; ++f) {
            const f32x4 a = f ? acc1 : acc0;
            float gi = a[0] + gxv[f][0];
            float gf = a[1] + gxv[f][1];
            float gg = a[2] + gxv[f][2];
            float go = a[3] + gxv[f][3];
            float cn = sigm(gf) * creg[f] + sigm(gi) * tanh_fast(gg);
            float hn = sigm(go) * tanh_fast(cn);
            if (act_m) creg[f] = cn;
            hn_patch[w][l15][4 * f + kg] = hn;
        }

        // wave-local transpose barrier (same-wave LDS ordering only)
        asm volatile("s_waitcnt lgkmcnt(0)" ::: "memory");
        __builtin_amdgcn_sched_barrier(0);

        // store phase: lanes 0..31, row sr, cols jc..jc+3
        if (is_store) {
            const bool act_r = (row0 + sr) < bs_t;
            float hn0 = hn_patch[w][sr][4 * ss + 0];
            float hn1 = hn_patch[w][sr][4 * ss + 1];
            float hn2 = hn_patch[w][sr][4 * ss + 2];
            float hn3 = hn_patch[w][sr][4 * ss + 3];
            float hv[4];
            hv[0] = act_r ? hn0 : hprev[0];
            hv[1] = act_r ? hn1 : hprev[1];
            hv[2] = act_r ? hn2 : hprev[2];
            hv[3] = act_r ? hn3 : hprev[3];
            if (owner) {
                if (act_r) { hxy0 = hn0; hxy1 = hn1; }
                else       { hv[0] = hxy0; hv[1] = hxy1; }
            }
            #pragma unroll
            for (int c = 0; c < 4; ++c) hprev[c] = hv[c];
            U64x1 sv;
            #pragma unroll
            for (int c = 0; c < 4; ++c) sv.v[c] = (__bf16)hv[c];
            astore64(base_n + (size_t)(row0 + sr) * HD + jc, sv.q);
            asm volatile("s_waitcnt vmcnt(0)" ::: "memory");
            __builtin_amdgcn_sched_barrier(0);
            if (lane == 0)
                __hip_atomic_store(&flags[mg * 64 + jb * 4 + w], t + 2,
                                   __ATOMIC_RELAXED, __HIP_MEMORY_SCOPE_AGENT);
            // outputs[t] (off the inter-block critical path; drains during poll)
            float4 q;
            q.x = act_r ? hn0 : 0.f; q.y = act_r ? hn1 : 0.f;
            q.z = act_r ? hn2 : 0.f; q.w = act_r ? hn3 : 0.f;
            *reinterpret_cast<float4*>(out + (size_t)t * (BM * HD)
                                       + (size_t)(row0 + sr) * HD + jc) = q;
        }
    }

    // ---------------- epilogue ----------------
    if (is_store) {
        float4 p;
        p.x = hprev[0]; p.y = hprev[1]; p.z = hprev[2]; p.w = hprev[3];
        *reinterpret_cast<float4*>(out + (size_t)TN * BM * HD
                                   + (size_t)(row0 + sr) * HD + jc) = p;
    }
    {
        float* cp = out + (size_t)TN * BM * HD + (size_t)BM * HD;
        #pragma unroll
        for (int f = 0; f < 2; ++f)
            cp[(size_t)(row0 + l15) * HD + j0 + 8 * w + 4 * f + kg] = creg[f];
    }
}

extern "C" void kernel_launch(void* const* d_in, const int* in_sizes, int n_in,
                              void* d_out, int out_size, void* d_ws, size_t ws_size,
                              hipStream_t stream) {
    const float* x_in = (const float*)d_in[0];
    const int*   bs   = (const int*)d_in[1];
    const float* h0   = (const float*)d_in[2];
    const float* c0   = (const float*)d_in[3];
    const float* tau  = (const float*)d_in[4];
    const float* Ww   = (const float*)d_in[5];
    const float* Wb   = (const float*)d_in[6];
    const float* Uw   = (const float*)d_in[7];
    float* out = (float*)d_out;

    int*    flags = (int*)d_ws;                      // 16 groups x 64 flags = 4 KB
    __bf16* hbuf  = (__bf16*)((char*)d_ws + 4096);   // 2 bufs x 256 x 512 bf16 = 512 KB

    (void)hipMemsetAsync(d_ws, 0, 4096, stream);

    hipLaunchKernelGGL(lstm_persist, dim3(256), dim3(256), 0, stream,
                       x_in, bs, h0, c0, tau, Ww, Wb, Uw, out, hbuf, flags);
}